// Round 3
// 181.002 us; speedup vs baseline: 1.0012x; 1.0012x over previous
//
#include <hip/hip_runtime.h>

#define T_N   131072
#define K_N   64
#define L_C   128
#define F_N   8
#define N_CH  (T_N / L_C)   /* 1024 chunks per direction */
#define WARM  96
#define EPS_F 1e-10f
#define OBS_MAX ((T_N - 1) * F_N)

#define LOG2E 1.4426950408889634f
#define NL2E  (-0.72134752044448170f)   /* -0.5*log2(e) */
#define LN2   0.6931471805599453f
#define LN2PI 1.8378770664093453f
/* warm-up-only emission pre-scale 2^16: keeps the scale-free recursion
   centered in fp32 (E[log2 em] ~ -16.4/step). MUST NOT be used in the
   store phase: the reference's a/(sum+EPS) has sum at RAW emission scale
   (~1.6e-5, dipping to ~1e-13 at chi^2 outliers), and EPS=1e-10 saturation
   at those dips is part of the reference output. Scaling S by 2^16 erased
   it -> the 6.6e-2 failures of rounds 0-1. */
#define EMSC  16.0f

typedef float v2f __attribute__((ext_vector_type(2)));
typedef unsigned uint2v __attribute__((ext_vector_type(2)));

#define DPPI(SRC, CTRL) __builtin_amdgcn_update_dpp(0, (SRC), (CTRL), 0xF, 0xF, true)
#define DPPF(SRC, CTRL) __int_as_float(DPPI(__float_as_int(SRC), (CTRL)))

/* ---- DPP wave64 sum: VALU-only ---- */
template <int CTRL>
__device__ __forceinline__ float dpp_add(float x) {
  int y = __builtin_amdgcn_update_dpp(0, __float_as_int(x), CTRL, 0xF, 0xF, true);
  return x + __int_as_float(y);
}
__device__ __forceinline__ float wave_sum64(float x) {
  x = dpp_add<0x111>(x);
  x = dpp_add<0x112>(x);
  x = dpp_add<0x114>(x);
  x = dpp_add<0x118>(x);
  x = dpp_add<0x142>(x);
  x = dpp_add<0x143>(x);
  return __int_as_float(__builtin_amdgcn_readlane(__float_as_int(x), 63));
}

/* polarity-independent butterfly sums via gfx950 permlane swaps:
   {d,s} = swap(x,x) splits the two lane-parity classes across d,s (in some
   pairing), so d+s == x + x[lane^16] (resp ^32) under every convention.
   VALU pipe: removes the two LGKM hops from the loop-carried matvec chain.
   (Rounds 0-1 produced bit-identical outputs with asm vs builtin forms ->
   both compile correctly; the correctness bug was EPS semantics, above.) */
#if __has_builtin(__builtin_amdgcn_permlane16_swap) && \
    __has_builtin(__builtin_amdgcn_permlane32_swap)
__device__ __forceinline__ float psum16(float x) {
  uint2v r = __builtin_amdgcn_permlane16_swap(__float_as_uint(x),
                                              __float_as_uint(x), false, false);
  return __uint_as_float(r.x) + __uint_as_float(r.y);
}
__device__ __forceinline__ float psum32(float x) {
  uint2v r = __builtin_amdgcn_permlane32_swap(__float_as_uint(x),
                                              __float_as_uint(x), false, false);
  return __uint_as_float(r.x) + __uint_as_float(r.y);
}
#else
__device__ __forceinline__ float psum16(float x) {
  return x + __int_as_float(
      __builtin_amdgcn_ds_swizzle(__float_as_int(x), 0x401F)); /* xor16 */
}
__device__ __forceinline__ float psum32(float x) {
  int addr = (((int)threadIdx.x ^ 32) & 63) << 2;
  return x + __int_as_float(
      __builtin_amdgcn_ds_bpermute(addr, __float_as_int(x)));  /* xor32 */
}
#endif

#define PKFMA(a, b, c) __builtin_elementwise_fma(a, b, c)

/* emission: exp2(cc + sum_f x*(x*civ + cmiv)); coeffs pre-scaled by -0.5*log2e */
__device__ __forceinline__ float em_pk(const float4& xa, const float4& xb,
                                       const v2f civ2[4], const v2f cmiv2[4],
                                       float cc) {
  v2f x0 = {xa.x, xa.y}, x1 = {xa.z, xa.w};
  v2f x2 = {xb.x, xb.y}, x3 = {xb.z, xb.w};
  v2f a0 = {cc, 0.f}, a1 = {0.f, 0.f};
  a0 = PKFMA(x0, PKFMA(x0, civ2[0], cmiv2[0]), a0);
  a1 = PKFMA(x1, PKFMA(x1, civ2[1], cmiv2[1]), a1);
  a0 = PKFMA(x2, PKFMA(x2, civ2[2], cmiv2[2]), a0);
  a1 = PKFMA(x3, PKFMA(x3, civ2[3], cmiv2[3]), a1);
  v2f s = a0 + a1;
  return __builtin_amdgcn_exp2f(s.x + s.y);
}

/* 64x64 matvec, state distributed (lane l holds VV = v[l]):
   gather 16 row-local values via DPP doubling; lane (q,h) accumulates
   partials for columns {h, h+16, h+32, h+48} over its 16-row group; full
   column sums via 2 butterfly-sum levels (lane^32, lane^16); select own
   column m = h + 16q == lane. */
#define MATVEC(VV, MOUT)                                                      \
  {                                                                           \
    float Gr[16];                                                             \
    Gr[0] = (VV);                                                             \
    Gr[1] = DPPF(Gr[0], 0xB1);                        /* quad xor1 */         \
    Gr[2] = DPPF(Gr[0], 0x4E);                        /* quad xor2 */         \
    Gr[3] = DPPF(Gr[1], 0x4E);                                                \
    _Pragma("unroll")                                                         \
    for (int rr = 0; rr < 4; ++rr) Gr[4 + rr] = DPPF(Gr[rr], 0x124);          \
    _Pragma("unroll")                                                         \
    for (int rr = 0; rr < 8; ++rr) Gr[8 + rr] = DPPF(Gr[rr], 0x128);          \
    v2f aE0 = {0.f,0.f}, aE1 = {0.f,0.f}, aO0 = {0.f,0.f}, aO1 = {0.f,0.f};   \
    _Pragma("unroll")                                                         \
    for (int rr = 0; rr < 8; ++rr) {                                          \
      v2f gg = {Gr[rr], Gr[rr]};                                              \
      aE0 = PKFMA(gg, TcE[rr], aE0);                                          \
      aO0 = PKFMA(gg, TcO[rr], aO0);                                          \
    }                                                                         \
    _Pragma("unroll")                                                         \
    for (int rr = 8; rr < 16; ++rr) {                                         \
      v2f gg = {Gr[rr], Gr[rr]};                                              \
      aE1 = PKFMA(gg, TcE[rr], aE1);                                          \
      aO1 = PKFMA(gg, TcO[rr], aO1);                                          \
    }                                                                         \
    v2f accE = aE0 + aE1, accO = aO0 + aO1;   /* E: m=0,2  O: m=1,3 */        \
    float pe0 = psum32(accE.x), pe2 = psum32(accE.y);                         \
    float po1 = psum32(accO.x), po3 = psum32(accO.y);                         \
    pe0 = psum16(pe0); pe2 = psum16(pe2);                                     \
    po1 = psum16(po1); po3 = psum16(po3);                                     \
    float tE = qb1 ? pe2 : pe0;                                               \
    float tO = qb1 ? po3 : po1;                                               \
    MOUT = qb0 ? tO : tE;                                                     \
  }

extern "C" __global__ void __launch_bounds__(64, 2)
hdphmm_fb(const float* __restrict__ obs,
          const float* __restrict__ beta_logits,
          const float* __restrict__ pi_logits,
          const float* __restrict__ means,
          const float* __restrict__ log_vars,
          float* __restrict__ out) {
  const int lane = threadIdx.x;
  const int bid  = blockIdx.x;
  const int h    = lane & 15;
  const bool qb0 = (lane >> 4) & 1;
  const bool qb1 = (lane >> 5) & 1;
  __shared__ __align__(8) float2 sstat[K_N];
  __shared__ float sb[K_N];

  float* alpha   = out;
  float* betaout = out + (size_t)T_N * K_N;

  /* ---- per-lane emission coefficients (lane == state), packed ---- */
  v2f civ2[4], cmiv2[4];
  float c0, cw;   /* c0: raw scale (store phase); cw: +2^16 (warm-up only) */
  {
    const float4* mp = reinterpret_cast<const float4*>(means + lane * F_N);
    const float4* lp = reinterpret_cast<const float4*>(log_vars + lane * F_N);
    float4 m0 = mp[0], m1 = mp[1];
    float4 l0 = lp[0], l1 = lp[1];
    float mu[8] = {m0.x, m0.y, m0.z, m0.w, m1.x, m1.y, m1.z, m1.w};
    float lv[8] = {l0.x, l0.y, l0.z, l0.w, l1.x, l1.y, l1.z, l1.w};
    float cst = F_N * LN2PI;
#pragma unroll
    for (int f = 0; f < 8; ++f) {
      float iv = __builtin_amdgcn_exp2f(-lv[f] * LOG2E);
      cst += lv[f] + mu[f] * mu[f] * iv;
      float cf  = NL2E * iv;
      civ2[f >> 1][f & 1]  = cf;
      cmiv2[f >> 1][f & 1] = -2.0f * mu[f] * cf;
    }
    c0 = NL2E * cst;
    cw = c0 + EMSC;
  }

  /* ---- softmax stats (max, 1/sum) of pi_logits row `lane` -> LDS ---- */
  {
    const float4* pr4 = reinterpret_cast<const float4*>(pi_logits + lane * K_N);
    float mx = -3.0e38f;
#pragma unroll
    for (int k = 0; k < 16; ++k) {
      float4 r = pr4[k];
      mx = fmaxf(mx, fmaxf(fmaxf(r.x, r.y), fmaxf(r.z, r.w)));
    }
    float s = 0.0f;
#pragma unroll
    for (int k = 0; k < 16; ++k) {
      float4 r = pr4[k];
      s += __builtin_amdgcn_exp2f((r.x - mx) * LOG2E);
      s += __builtin_amdgcn_exp2f((r.y - mx) * LOG2E);
      s += __builtin_amdgcn_exp2f((r.z - mx) * LOG2E);
      s += __builtin_amdgcn_exp2f((r.w - mx) * LOG2E);
    }
    sstat[lane] = make_float2(mx, __builtin_amdgcn_rcpf(s));
  }
  __syncthreads();

  /* ---- gather k-indices BY CONSTRUCTION: same DPP chain on lane id ---- */
  int ki[16];
  ki[0] = lane;
  ki[1] = DPPI(ki[0], 0xB1);
  ki[2] = DPPI(ki[0], 0x4E);
  ki[3] = DPPI(ki[1], 0x4E);
#pragma unroll
  for (int rr = 0; rr < 4; ++rr) ki[4 + rr] = DPPI(ki[rr], 0x124);
#pragma unroll
  for (int rr = 0; rr < 8; ++rr) ki[8 + rr] = DPPI(ki[rr], 0x128);

  if (bid < N_CH) {
    /* ================= FORWARD chunk ================= */
    v2f TcE[16], TcO[16];
#pragma unroll
    for (int rr = 0; rr < 16; ++rr) {
      int k = ki[rr];
      float2 st = sstat[k];
      const float* pk = pi_logits + k * K_N;
      float e0 = __builtin_amdgcn_exp2f((pk[h]      - st.x) * LOG2E) * st.y;
      float e1 = __builtin_amdgcn_exp2f((pk[h + 16] - st.x) * LOG2E) * st.y;
      float e2 = __builtin_amdgcn_exp2f((pk[h + 32] - st.x) * LOG2E) * st.y;
      float e3 = __builtin_amdgcn_exp2f((pk[h + 48] - st.x) * LOG2E) * st.y;
      TcE[rr] = (v2f){e0, e2};
      TcO[rr] = (v2f){e1, e3};
    }

    const int out_lo = bid * L_C;
    float v;
    int t_first;
    if (bid == 0) {
      /* exact stick-breaking init at RAW scale (reference EPS semantics) */
      float bl = beta_logits[lane];
      float ex = __builtin_amdgcn_exp2f(-bl * LOG2E);
      float bw = __builtin_amdgcn_rcpf(1.0f + ex);
      sb[lane] = 1.0f - bw;
      __syncthreads();
      float pr = 1.0f;
#pragma unroll
      for (int i = 0; i < 64; ++i) {
        float qv = sb[i];
        pr = (i < lane) ? pr * qv : pr;
      }
      float4 x0 = reinterpret_cast<const float4*>(obs)[0];
      float4 x1 = reinterpret_cast<const float4*>(obs)[1];
      v = bw * pr * em_pk(x0, x1, civ2, cmiv2, c0);
      t_first = 1;
    } else {
      const int t0 = out_lo - WARM;
      const float4* xp = reinterpret_cast<const float4*>(obs + t0 * F_N);
      v = em_pk(xp[0], xp[1], civ2, cmiv2, cw);   /* flat warm start, scaled */
      t_first = t0 + 1;
    }
    int obs_off = t_first * F_N;
    float4 xa, xb;
    {
      const float4* xp = reinterpret_cast<const float4*>(obs + obs_off);
      xa = xp[0]; xb = xp[1];
    }
    int out_off = out_lo * K_N + lane;

    /* ---- warm-up: scale-free recursion (scaled em), rescale every 8;
       final rescale lands exactly on step 96 -> sum(v)=1 at store entry ---- */
    const int wn8 = (bid == 0) ? 0 : (WARM >> 3);
#pragma unroll 1
    for (int o = 0; o < wn8; ++o) {
#pragma unroll
      for (int i = 0; i < 8; ++i) {
        float4 nxa = *reinterpret_cast<const float4*>(obs + obs_off + F_N);
        float4 nxb = *reinterpret_cast<const float4*>(obs + obs_off + F_N + 4);
        float m;
        MATVEC(v, m)
        float e = em_pk(xa, xb, civ2, cmiv2, cw);
        v = m * e;
        xa = nxa; xb = nxb; obs_off += F_N;
      }
      float Sw = wave_sum64(v);
      v *= __builtin_amdgcn_rcpf(Sw);
    }

    /* ---- store phase: RAW-scale em, reference EPS semantics ---- */
    float S = wave_sum64(v);
    float r_st = __builtin_amdgcn_rcpf(S + EPS_F);

#define FWD_SSTEP                                                             \
  {                                                                           \
    int offn = obs_off + F_N; offn = (offn > OBS_MAX) ? OBS_MAX : offn;       \
    float4 nxa = *reinterpret_cast<const float4*>(obs + offn);                \
    float4 nxb = *reinterpret_cast<const float4*>(obs + offn + 4);            \
    float m;                                                                  \
    MATVEC(v, m)                                                              \
    alpha[out_off] = v * r_st; out_off += K_N;                                \
    float e = em_pk(xa, xb, civ2, cmiv2, c0);                                 \
    float vn = m * (r_st * e);                                                \
    S = wave_sum64(vn);                                                       \
    r_st = __builtin_amdgcn_rcpf(S + EPS_F);                                  \
    v = vn; xa = nxa; xb = nxb; obs_off = offn;                               \
  }

#pragma unroll 2
    for (int it = 0; it < L_C - 1; ++it) FWD_SSTEP
#undef FWD_SSTEP
    alpha[out_off] = v * r_st;
    if (bid == N_CH - 1 && lane == 0) {
      float sl = S * r_st + EPS_F;
      out[(size_t)2 * T_N * K_N] = __builtin_amdgcn_logf(sl) * LN2;
    }
  } else {
    /* ================= BACKWARD chunk ================= */
    v2f TcE[16], TcO[16];
    {
      float2 s0 = sstat[h], s1 = sstat[h + 16];
      float2 s2 = sstat[h + 32], s3 = sstat[h + 48];
#pragma unroll
      for (int rr = 0; rr < 16; ++rr) {
        int k = ki[rr];
        float p0 = pi_logits[h * K_N + k];
        float p1 = pi_logits[(h + 16) * K_N + k];
        float p2 = pi_logits[(h + 32) * K_N + k];
        float p3 = pi_logits[(h + 48) * K_N + k];
        TcE[rr] = (v2f){__builtin_amdgcn_exp2f((p0 - s0.x) * LOG2E) * s0.y,
                        __builtin_amdgcn_exp2f((p2 - s2.x) * LOG2E) * s2.y};
        TcO[rr] = (v2f){__builtin_amdgcn_exp2f((p1 - s1.x) * LOG2E) * s1.y,
                        __builtin_amdgcn_exp2f((p3 - s3.x) * LOG2E) * s3.y};
      }
    }
    const int cb   = bid - N_CH;
    const int t_lo = cb * L_C;
    const int t_hi = t_lo + L_C - 1;
    int t_top = t_hi + WARM;
    if (t_top > T_N - 1) t_top = T_N - 1;        /* clamp => exact bT anchor */
    const int s_top = (cb == N_CH - 1) ? T_N - 2 : t_hi;

    float w;
    {
      const float4* xp = reinterpret_cast<const float4*>(obs + t_top * F_N);
      w = em_pk(xp[0], xp[1], civ2, cmiv2, cw);   /* scale divided out later */
    }
    if (cb == N_CH - 1)
      betaout[(size_t)(T_N - 1) * K_N + lane] = 1.0f;
    int obs_off = (t_top - 1) * F_N;
    float4 xa, xb;
    {
      const float4* xp = reinterpret_cast<const float4*>(obs + obs_off);
      xa = xp[0]; xb = xp[1];
    }
    int out_off = s_top * K_N + lane;

    /* ---- warm-up (scale-free, scaled em), pw = warm_n - 1 steps ---- */
#define BWD_WSTEP                                                             \
  {                                                                           \
    float4 nxa = *reinterpret_cast<const float4*>(obs + obs_off - F_N);       \
    float4 nxb = *reinterpret_cast<const float4*>(obs + obs_off - F_N + 4);   \
    float m;                                                                  \
    MATVEC(w, m)                                                              \
    float e = em_pk(xa, xb, civ2, cmiv2, cw);                                 \
    w = m * e;                                                                \
    xa = nxa; xb = nxb; obs_off -= F_N;                                       \
  }

    const int pw  = (t_top - s_top) - 1;         /* 95 generic, 0 last chunk */
    const int pw8 = pw >> 3, pwr = pw & 7;
#pragma unroll 1
    for (int o = 0; o < pw8; ++o) {
#pragma unroll
      for (int i = 0; i < 8; ++i) BWD_WSTEP
      float Sw = wave_sum64(w);
      w *= __builtin_amdgcn_rcpf(Sw);
    }
#pragma unroll 1
    for (int it = 0; it < pwr; ++it) BWD_WSTEP
#undef BWD_WSTEP

    /* ---- transition (the warm_n-th step): exact direction normalize,
       switch to RAW-scale em so store phase has reference EPS semantics ---- */
    float u, S, r_st;
    {
      float m;
      MATVEC(w, m)
      float Sm = wave_sum64(m);
      u = m * __builtin_amdgcn_rcpf(Sm);          /* b(s_top), sum == 1 */
      float e = em_pk(xa, xb, civ2, cmiv2, c0);   /* em[s_top], raw scale */
      w = u * e;
      S = wave_sum64(u);
      r_st = __builtin_amdgcn_rcpf(S + EPS_F);
      int offn = obs_off - F_N; offn = (offn < 0) ? 0 : offn;
      xa = *reinterpret_cast<const float4*>(obs + offn);
      xb = *reinterpret_cast<const float4*>(obs + offn + 4);
      obs_off = offn;
    }

#define BWD_SSTEP                                                             \
  {                                                                           \
    int offn = obs_off - F_N; offn = (offn < 0) ? 0 : offn;                   \
    float4 nxa = *reinterpret_cast<const float4*>(obs + offn);                \
    float4 nxb = *reinterpret_cast<const float4*>(obs + offn + 4);            \
    float m;                                                                  \
    MATVEC(w, m)                                                              \
    betaout[out_off] = u * r_st; out_off -= K_N;                              \
    float u2 = m * r_st;                                                      \
    float e = em_pk(xa, xb, civ2, cmiv2, c0);                                 \
    w = u2 * e;                                                               \
    S = wave_sum64(u2);                                                       \
    r_st = __builtin_amdgcn_rcpf(S + EPS_F);                                  \
    u = u2; xa = nxa; xb = nxb; obs_off = offn;                               \
  }

    const int store_n = s_top - t_lo;
#pragma unroll 2
    for (int it = 0; it < store_n; ++it) BWD_SSTEP
#undef BWD_SSTEP
    betaout[t_lo * K_N + lane] = u * r_st;
  }
}

extern "C" void kernel_launch(void* const* d_in, const int* in_sizes, int n_in,
                              void* d_out, int out_size, void* d_ws, size_t ws_size,
                              hipStream_t stream) {
  (void)in_sizes; (void)n_in; (void)out_size; (void)d_ws; (void)ws_size;
  const float* obs  = (const float*)d_in[0];
  const float* bl   = (const float*)d_in[1];
  const float* pi   = (const float*)d_in[2];
  const float* mns  = (const float*)d_in[3];
  const float* lvs  = (const float*)d_in[4];
  hipLaunchKernelGGL(hdphmm_fb, dim3(2 * N_CH), dim3(64), 0, stream,
                     obs, bl, pi, mns, lvs, (float*)d_out);
}